// Round 1
// baseline (1661.857 us; speedup 1.0000x reference)
//
#include <hip/hip_runtime.h>

#define N_NODES 100000
#define N_EDGES 1600000
#define IN_CH 256
#define HID_CH 128

// ---------------- degree / norm ----------------

__global__ void init_deg_kernel(float* __restrict__ deg) {
    int i = blockIdx.x * blockDim.x + threadIdx.x;
    if (i < N_NODES) deg[i] = 1.0f;  // self loop
}

__global__ void degree_kernel(const int* __restrict__ col, float* __restrict__ deg) {
    int e = blockIdx.x * blockDim.x + threadIdx.x;
    if (e < N_EDGES) unsafeAtomicAdd(&deg[col[e]], 1.0f);
}

__global__ void rsqrt_kernel(float* __restrict__ deg) {
    int i = blockIdx.x * blockDim.x + threadIdx.x;
    if (i < N_NODES) deg[i] = rsqrtf(deg[i]);  // deg >= 1 always (self loop)
}

// ---------------- GEMM: h = x @ W  (fp32, LDS-tiled) ----------------
// Block: 64 rows x 128 cols, BK=32. 256 threads, each computes 4x8 microtile.

#define BM 64
#define BK 32

__launch_bounds__(256)
__global__ void gemm_kernel(const float* __restrict__ x, const float* __restrict__ W,
                            float* __restrict__ h) {
    __shared__ float xs[BK][BM + 1];    // transposed x tile, +1 pad
    __shared__ float ws[BK][HID_CH];    // W tile

    const int tid = threadIdx.x;
    const int block_row = blockIdx.x * BM;
    const int tx = tid & 15;   // 16 col groups of 8
    const int ty = tid >> 4;   // 16 row groups of 4

    float acc[4][8] = {};

    for (int k0 = 0; k0 < IN_CH; k0 += BK) {
        // load x tile: 64 rows x 32 k = 512 float4
#pragma unroll
        for (int i = 0; i < 2; ++i) {
            int f = tid + i * 256;         // 0..511
            int r = f >> 3;                // row within tile
            int k4 = f & 7;                // which float4 along k
            int row = block_row + r;
            float4 v = make_float4(0.f, 0.f, 0.f, 0.f);
            if (row < N_NODES)
                v = *(const float4*)&x[(long long)row * IN_CH + k0 + k4 * 4];
            xs[k4 * 4 + 0][r] = v.x;
            xs[k4 * 4 + 1][r] = v.y;
            xs[k4 * 4 + 2][r] = v.z;
            xs[k4 * 4 + 3][r] = v.w;
        }
        // load W tile: 32 k x 128 c = 1024 float4
#pragma unroll
        for (int i = 0; i < 4; ++i) {
            int f = tid + i * 256;         // 0..1023
            int k = f >> 5;                // k row
            int c4 = f & 31;               // which float4 along c
            float4 v = *(const float4*)&W[(long long)(k0 + k) * HID_CH + c4 * 4];
            *(float4*)&ws[k][c4 * 4] = v;
        }
        __syncthreads();

#pragma unroll
        for (int kk = 0; kk < BK; ++kk) {
            float a[4], b[8];
#pragma unroll
            for (int i = 0; i < 4; ++i) a[i] = xs[kk][ty * 4 + i];
#pragma unroll
            for (int j = 0; j < 8; ++j) b[j] = ws[kk][tx * 8 + j];
#pragma unroll
            for (int i = 0; i < 4; ++i)
#pragma unroll
                for (int j = 0; j < 8; ++j) acc[i][j] += a[i] * b[j];
        }
        __syncthreads();
    }

#pragma unroll
    for (int i = 0; i < 4; ++i) {
        int row = block_row + ty * 4 + i;
        if (row < N_NODES) {
            float4 v0 = make_float4(acc[i][0], acc[i][1], acc[i][2], acc[i][3]);
            float4 v1 = make_float4(acc[i][4], acc[i][5], acc[i][6], acc[i][7]);
            *(float4*)&h[(long long)row * HID_CH + tx * 8] = v0;
            *(float4*)&h[(long long)row * HID_CH + tx * 8 + 4] = v1;
        }
    }
}

// ---------------- edge scatter: agg[col] += norm * h[row] ----------------
// One wave (64 lanes) per edge; each lane owns 2 channels (float2).

__launch_bounds__(256)
__global__ void scatter_kernel(const int* __restrict__ ei, const float* __restrict__ dinv,
                               const float* __restrict__ h, float* __restrict__ out) {
    long long t = (long long)blockIdx.x * blockDim.x + threadIdx.x;
    int e = (int)(t >> 6);
    int lane = (int)(t & 63);
    if (e >= N_EDGES) return;
    int src = ei[e];             // row (source j)
    int dst = ei[N_EDGES + e];   // col (target i)
    float norm = dinv[src] * dinv[dst];
    float2 v = *(const float2*)&h[(long long)src * HID_CH + lane * 2];
    float* p = &out[(long long)dst * HID_CH + lane * 2];
    unsafeAtomicAdd(p, v.x * norm);
    unsafeAtomicAdd(p + 1, v.y * norm);
}

// ---------------- finalize: out = PReLU(agg + dinv^2*h + bias) ----------------

__launch_bounds__(256)
__global__ void finalize_kernel(float* __restrict__ out, const float* __restrict__ h,
                                const float* __restrict__ dinv,
                                const float* __restrict__ bias,
                                const float* __restrict__ alpha) {
    int t = blockIdx.x * blockDim.x + threadIdx.x;   // over N*HID/4
    if (t >= N_NODES * (HID_CH / 4)) return;
    int node = t >> 5;            // 32 float4 per node
    int c4 = (t & 31) * 4;
    float di = dinv[node];
    float s = di * di;            // self-loop norm
    float4 hv = *(const float4*)&h[(long long)t * 4];
    float4 ov = *(const float4*)&out[(long long)t * 4];
    float4 bv = *(const float4*)&bias[c4];
    float4 av = *(const float4*)&alpha[c4];
    float r0 = ov.x + s * hv.x + bv.x;
    float r1 = ov.y + s * hv.y + bv.y;
    float r2 = ov.z + s * hv.z + bv.z;
    float r3 = ov.w + s * hv.w + bv.w;
    float4 res;
    res.x = r0 > 0.f ? r0 : av.x * r0;
    res.y = r1 > 0.f ? r1 : av.y * r1;
    res.z = r2 > 0.f ? r2 : av.z * r2;
    res.w = r3 > 0.f ? r3 : av.w * r3;
    *(float4*)&out[(long long)t * 4] = res;
}

// ---------------- launch ----------------

extern "C" void kernel_launch(void* const* d_in, const int* in_sizes, int n_in,
                              void* d_out, int out_size, void* d_ws, size_t ws_size,
                              hipStream_t stream) {
    const float* x     = (const float*)d_in[0];
    const int*   ei    = (const int*)d_in[1];     // [2, E] flat: [0..E)=src, [E..2E)=dst
    const float* W     = (const float*)d_in[2];
    const float* bias  = (const float*)d_in[3];
    const float* alpha = (const float*)d_in[4];
    float* out = (float*)d_out;

    // workspace layout: deg/dinv (N floats), then h (N*HID floats), 512B aligned
    float* deg = (float*)d_ws;
    size_t h_off = ((size_t)N_NODES * 4 + 511) / 512 * 512;
    float* h = (float*)((char*)d_ws + h_off);

    // agg accumulates directly in d_out
    hipMemsetAsync(d_out, 0, (size_t)N_NODES * HID_CH * sizeof(float), stream);

    init_deg_kernel<<<(N_NODES + 255) / 256, 256, 0, stream>>>(deg);
    degree_kernel<<<(N_EDGES + 255) / 256, 256, 0, stream>>>(ei + N_EDGES, deg);
    rsqrt_kernel<<<(N_NODES + 255) / 256, 256, 0, stream>>>(deg);

    gemm_kernel<<<(N_NODES + BM - 1) / BM, 256, 0, stream>>>(x, W, h);

    long long sthreads = (long long)N_EDGES * 64;
    scatter_kernel<<<(int)((sthreads + 255) / 256), 256, 0, stream>>>(ei, deg, h, out);

    finalize_kernel<<<(N_NODES * (HID_CH / 4) + 255) / 256, 256, 0, stream>>>(
        out, h, deg, bias, alpha);
}

// Round 2
// 565.723 us; speedup vs baseline: 2.9376x; 2.9376x over previous
//
#include <hip/hip_runtime.h>

#define N_NODES 100000
#define N_EDGES 1600000
#define IN_CH 256
#define HID_CH 128
#define SCAN_BLOCKS ((N_NODES + 255) / 256)   // 391

// ---------------- CSR build ----------------

__global__ void count_kernel(const int* __restrict__ dst, int* __restrict__ counts) {
    int e = blockIdx.x * blockDim.x + threadIdx.x;
    if (e < N_EDGES) atomicAdd(&counts[dst[e]], 1);
}

// Per-block exclusive scan; block sums to partials.
__global__ void scanA_kernel(const int* __restrict__ counts, int* __restrict__ row_start,
                             int* __restrict__ partials) {
    __shared__ int ss[256];
    int tid = threadIdx.x;
    int i = blockIdx.x * 256 + tid;
    int v = (i < N_NODES) ? counts[i] : 0;
    ss[tid] = v;
    __syncthreads();
    for (int off = 1; off < 256; off <<= 1) {
        int t = (tid >= off) ? ss[tid - off] : 0;
        __syncthreads();
        ss[tid] += t;
        __syncthreads();
    }
    if (i < N_NODES) row_start[i] = ss[tid] - v;   // exclusive within block
    if (tid == 255) partials[blockIdx.x] = ss[255];
}

// Scan the 391 block partials in one block (512 threads), in place -> exclusive.
__global__ void scanB_kernel(int* __restrict__ partials) {
    __shared__ int ss[512];
    int tid = threadIdx.x;
    int v = (tid < SCAN_BLOCKS) ? partials[tid] : 0;
    ss[tid] = v;
    __syncthreads();
    for (int off = 1; off < 512; off <<= 1) {
        int t = (tid >= off) ? ss[tid - off] : 0;
        __syncthreads();
        ss[tid] += t;
        __syncthreads();
    }
    if (tid < SCAN_BLOCKS) partials[tid] = ss[tid] - v;  // exclusive
}

// Add block offsets; init cursor; compute dinv; write sentinel.
__global__ void scanC_kernel(int* __restrict__ row_start, const int* __restrict__ partials,
                             int* __restrict__ cursor, const int* __restrict__ counts,
                             float* __restrict__ dinv) {
    int i = blockIdx.x * 256 + threadIdx.x;
    if (i >= N_NODES) return;
    int s = row_start[i] + partials[blockIdx.x];
    row_start[i] = s;
    cursor[i] = s;
    dinv[i] = rsqrtf((float)(counts[i] + 1));   // +1 self loop
    if (i == 0) row_start[N_NODES] = N_EDGES;
}

__global__ void reorder_kernel(const int* __restrict__ ei, int* __restrict__ cursor,
                               int* __restrict__ sorted) {
    int e = blockIdx.x * blockDim.x + threadIdx.x;
    if (e >= N_EDGES) return;
    int dst = ei[N_EDGES + e];
    int pos = atomicAdd(&cursor[dst], 1);
    sorted[pos] = ei[e];   // src
}

// ---------------- GEMM: h = x @ W  (fp32, LDS-tiled) ----------------

#define BM 64
#define BK 32

__launch_bounds__(256)
__global__ void gemm_kernel(const float* __restrict__ x, const float* __restrict__ W,
                            float* __restrict__ h) {
    __shared__ float xs[BK][BM + 1];
    __shared__ float ws[BK][HID_CH];

    const int tid = threadIdx.x;
    const int block_row = blockIdx.x * BM;
    const int tx = tid & 15;
    const int ty = tid >> 4;

    float acc[4][8] = {};

    for (int k0 = 0; k0 < IN_CH; k0 += BK) {
#pragma unroll
        for (int i = 0; i < 2; ++i) {
            int f = tid + i * 256;
            int r = f >> 3;
            int k4 = f & 7;
            int row = block_row + r;
            float4 v = make_float4(0.f, 0.f, 0.f, 0.f);
            if (row < N_NODES)
                v = *(const float4*)&x[(long long)row * IN_CH + k0 + k4 * 4];
            xs[k4 * 4 + 0][r] = v.x;
            xs[k4 * 4 + 1][r] = v.y;
            xs[k4 * 4 + 2][r] = v.z;
            xs[k4 * 4 + 3][r] = v.w;
        }
#pragma unroll
        for (int i = 0; i < 4; ++i) {
            int f = tid + i * 256;
            int k = f >> 5;
            int c4 = f & 31;
            float4 v = *(const float4*)&W[(long long)(k0 + k) * HID_CH + c4 * 4];
            *(float4*)&ws[k][c4 * 4] = v;
        }
        __syncthreads();

#pragma unroll
        for (int kk = 0; kk < BK; ++kk) {
            float a[4], b[8];
#pragma unroll
            for (int i = 0; i < 4; ++i) a[i] = xs[kk][ty * 4 + i];
#pragma unroll
            for (int j = 0; j < 8; ++j) b[j] = ws[kk][tx * 8 + j];
#pragma unroll
            for (int i = 0; i < 4; ++i)
#pragma unroll
                for (int j = 0; j < 8; ++j) acc[i][j] += a[i] * b[j];
        }
        __syncthreads();
    }

#pragma unroll
    for (int i = 0; i < 4; ++i) {
        int row = block_row + ty * 4 + i;
        if (row < N_NODES) {
            float4 v0 = make_float4(acc[i][0], acc[i][1], acc[i][2], acc[i][3]);
            float4 v1 = make_float4(acc[i][4], acc[i][5], acc[i][6], acc[i][7]);
            *(float4*)&h[(long long)row * HID_CH + tx * 8] = v0;
            *(float4*)&h[(long long)row * HID_CH + tx * 8 + 4] = v1;
        }
    }
}

// ---------------- gather + finalize (fused) ----------------
// One wave per node. Lane owns 2 channels. No atomics.

__launch_bounds__(256)
__global__ void gather_finalize_kernel(const int* __restrict__ row_start,
                                       const int* __restrict__ sorted,
                                       const float* __restrict__ dinv,
                                       const float* __restrict__ h,
                                       const float* __restrict__ bias,
                                       const float* __restrict__ alpha,
                                       float* __restrict__ out) {
    int node = (blockIdx.x * blockDim.x + threadIdx.x) >> 6;
    int lane = threadIdx.x & 63;
    if (node >= N_NODES) return;

    int k = row_start[node];
    int end = row_start[node + 1];
    float di = dinv[node];
    float accx = 0.f, accy = 0.f;

    int s_next = (k < end) ? sorted[k] : 0;
    while (k < end) {
        int s = s_next;
        ++k;
        if (k < end) s_next = sorted[k];
        float nrm = di * dinv[s];
        float2 v = *(const float2*)&h[(long long)s * HID_CH + lane * 2];
        accx += nrm * v.x;
        accy += nrm * v.y;
    }

    // self loop + bias
    float2 hv = *(const float2*)&h[(long long)node * HID_CH + lane * 2];
    float2 bv = *(const float2*)&bias[lane * 2];
    float2 av = *(const float2*)&alpha[lane * 2];
    float s2 = di * di;
    float r0 = accx + s2 * hv.x + bv.x;
    float r1 = accy + s2 * hv.y + bv.y;
    float2 res;
    res.x = r0 > 0.f ? r0 : av.x * r0;
    res.y = r1 > 0.f ? r1 : av.y * r1;
    *(float2*)&out[(long long)node * HID_CH + lane * 2] = res;
}

// ---------------- launch ----------------

extern "C" void kernel_launch(void* const* d_in, const int* in_sizes, int n_in,
                              void* d_out, int out_size, void* d_ws, size_t ws_size,
                              hipStream_t stream) {
    const float* x     = (const float*)d_in[0];
    const int*   ei    = (const int*)d_in[1];     // [2, E]: [0..E)=src, [E..2E)=dst
    const float* W     = (const float*)d_in[2];
    const float* bias  = (const float*)d_in[3];
    const float* alpha = (const float*)d_in[4];
    float* out = (float*)d_out;

    // workspace layout (4-byte units), 512 B aligned chunks
    char* p = (char*)d_ws;
    auto align512 = [](size_t v) { return (v + 511) / 512 * 512; };
    float* h      = (float*)p;  p += align512((size_t)N_NODES * HID_CH * 4);
    int* counts   = (int*)p;    p += align512((size_t)N_NODES * 4);
    float* dinv   = (float*)p;  p += align512((size_t)N_NODES * 4);
    int* row_start= (int*)p;    p += align512((size_t)(N_NODES + 1) * 4);
    int* cursor   = (int*)p;    p += align512((size_t)N_NODES * 4);
    int* partials = (int*)p;    p += align512(512 * 4);
    int* sorted   = (int*)p;    p += align512((size_t)N_EDGES * 4);

    hipMemsetAsync(counts, 0, (size_t)N_NODES * sizeof(int), stream);

    count_kernel<<<(N_EDGES + 255) / 256, 256, 0, stream>>>(ei + N_EDGES, counts);
    scanA_kernel<<<SCAN_BLOCKS, 256, 0, stream>>>(counts, row_start, partials);
    scanB_kernel<<<1, 512, 0, stream>>>(partials);
    scanC_kernel<<<SCAN_BLOCKS, 256, 0, stream>>>(row_start, partials, cursor, counts, dinv);
    reorder_kernel<<<(N_EDGES + 255) / 256, 256, 0, stream>>>(ei, cursor, sorted);

    gemm_kernel<<<(N_NODES + BM - 1) / BM, 256, 0, stream>>>(x, W, h);

    long long gthreads = (long long)N_NODES * 64;
    gather_finalize_kernel<<<(int)((gthreads + 255) / 256), 256, 0, stream>>>(
        row_start, sorted, dinv, h, bias, alpha, out);
}

// Round 3
// 397.494 us; speedup vs baseline: 4.1808x; 1.4232x over previous
//
#include <hip/hip_runtime.h>

#define N_NODES 100000
#define N_EDGES 1600000
#define IN_CH 256
#define HID_CH 128
#define SCAN_BLOCKS ((N_NODES + 255) / 256)   // 391

typedef __attribute__((ext_vector_type(8))) short short8;
typedef __attribute__((ext_vector_type(4))) float floatx4;

// fp32 -> bf16 round-to-nearest-even
static __device__ __forceinline__ unsigned short f2bf(float f) {
    unsigned int u = __float_as_uint(f);
    u += 0x7fffu + ((u >> 16) & 1u);
    return (unsigned short)(u >> 16);
}

// ---------------- CSR build ----------------

// counts + per-edge rank in one pass
__global__ void count_kernel(const int* __restrict__ dst, int* __restrict__ counts,
                             int* __restrict__ rank) {
    int e = blockIdx.x * blockDim.x + threadIdx.x;
    if (e < N_EDGES) rank[e] = atomicAdd(&counts[dst[e]], 1);
}

__global__ void scanA_kernel(const int* __restrict__ counts, int* __restrict__ row_start,
                             int* __restrict__ partials) {
    __shared__ int ss[256];
    int tid = threadIdx.x;
    int i = blockIdx.x * 256 + tid;
    int v = (i < N_NODES) ? counts[i] : 0;
    ss[tid] = v;
    __syncthreads();
    for (int off = 1; off < 256; off <<= 1) {
        int t = (tid >= off) ? ss[tid - off] : 0;
        __syncthreads();
        ss[tid] += t;
        __syncthreads();
    }
    if (i < N_NODES) row_start[i] = ss[tid] - v;
    if (tid == 255) partials[blockIdx.x] = ss[255];
}

__global__ void scanB_kernel(int* __restrict__ partials) {
    __shared__ int ss[512];
    int tid = threadIdx.x;
    int v = (tid < SCAN_BLOCKS) ? partials[tid] : 0;
    ss[tid] = v;
    __syncthreads();
    for (int off = 1; off < 512; off <<= 1) {
        int t = (tid >= off) ? ss[tid - off] : 0;
        __syncthreads();
        ss[tid] += t;
        __syncthreads();
    }
    if (tid < SCAN_BLOCKS) partials[tid] = ss[tid] - v;
}

__global__ void scanC_kernel(int* __restrict__ row_start, const int* __restrict__ partials,
                             const int* __restrict__ counts, float* __restrict__ dinv) {
    int i = blockIdx.x * 256 + threadIdx.x;
    if (i >= N_NODES) return;
    row_start[i] += partials[blockIdx.x];
    dinv[i] = rsqrtf((float)(counts[i] + 1));   // +1 self loop
    if (i == 0) row_start[N_NODES] = N_EDGES;
}

// atomic-free reorder: pos known from rank
__global__ void reorder_kernel(const int* __restrict__ ei, const int* __restrict__ rank,
                               const int* __restrict__ row_start, int* __restrict__ sorted) {
    int e = blockIdx.x * blockDim.x + threadIdx.x;
    if (e >= N_EDGES) return;
    int dst = ei[N_EDGES + e];
    sorted[row_start[dst] + rank[e]] = ei[e];
}

// ---------------- W^T -> bf16 (one-time, 32K elems) ----------------

__global__ void wt_kernel(const float* __restrict__ W, unsigned short* __restrict__ Wt) {
    int i = blockIdx.x * blockDim.x + threadIdx.x;   // over IN_CH*HID_CH
    if (i >= IN_CH * HID_CH) return;
    int k = i >> 7;          // IN index
    int c = i & 127;         // HID index
    Wt[c * IN_CH + k] = f2bf(W[i]);
}

// ---------------- MFMA GEMM: hp = bf16( dinv[row] * (x @ W) ) ----------------
// One wave = 16 rows x 128 cols. No LDS, no barriers. A-frags straight from
// global fp32 x (converted in-reg); B-frags from L2-resident bf16 Wt.

__launch_bounds__(256)
__global__ void gemm_mfma_kernel(const float* __restrict__ x,
                                 const unsigned short* __restrict__ Wt,
                                 const float* __restrict__ dinv,
                                 unsigned short* __restrict__ hp) {
    int gwave = (blockIdx.x * blockDim.x + threadIdx.x) >> 6;
    int lane = threadIdx.x & 63;
    int row0 = gwave * 16;
    if (row0 >= N_NODES) return;

    int m = lane & 15;
    int q = lane >> 4;

    int arow = row0 + m;
    if (arow >= N_NODES) arow = N_NODES - 1;   // clamp; stores masked below

    floatx4 acc[8];
#pragma unroll
    for (int t = 0; t < 8; ++t) acc[t] = (floatx4){0.f, 0.f, 0.f, 0.f};

#pragma unroll
    for (int k0 = 0; k0 < IN_CH; k0 += 32) {
        const float* xp = &x[(size_t)arow * IN_CH + k0 + q * 8];
        float4 a0 = *(const float4*)xp;
        float4 a1 = *(const float4*)(xp + 4);
        short8 af;
        af[0] = (short)f2bf(a0.x); af[1] = (short)f2bf(a0.y);
        af[2] = (short)f2bf(a0.z); af[3] = (short)f2bf(a0.w);
        af[4] = (short)f2bf(a1.x); af[5] = (short)f2bf(a1.y);
        af[6] = (short)f2bf(a1.z); af[7] = (short)f2bf(a1.w);
#pragma unroll
        for (int t = 0; t < 8; ++t) {
            short8 bf = *(const short8*)&Wt[(size_t)(t * 16 + m) * IN_CH + k0 + q * 8];
            acc[t] = __builtin_amdgcn_mfma_f32_16x16x32_bf16(af, bf, acc[t], 0, 0, 0);
        }
    }

    // C/D layout: col = lane&15 (=m), row = q*4 + reg
#pragma unroll
    for (int reg = 0; reg < 4; ++reg) {
        int grow = row0 + q * 4 + reg;
        if (grow < N_NODES) {
            float di = dinv[grow];
#pragma unroll
            for (int t = 0; t < 8; ++t)
                hp[(size_t)grow * HID_CH + t * 16 + m] = f2bf(acc[t][reg] * di);
        }
    }
}

// ---------------- gather + finalize ----------------
// One wave per node, 4 edges in flight (16 lanes x 8 channels x 16B each).

__launch_bounds__(256)
__global__ void gather_finalize_kernel(const int* __restrict__ row_start,
                                       const int* __restrict__ sorted,
                                       const float* __restrict__ dinv,
                                       const unsigned short* __restrict__ hp,
                                       const float* __restrict__ bias,
                                       const float* __restrict__ alpha,
                                       float* __restrict__ out) {
    int node = (blockIdx.x * blockDim.x + threadIdx.x) >> 6;
    int lane = threadIdx.x & 63;
    if (node >= N_NODES) return;

    int beg = row_start[node];
    int end = row_start[node + 1];
    int part = lane >> 4;          // 0..3: which edge of the group of 4
    int ch = (lane & 15) * 8;      // 8 channels per lane

    float acc[8];
#pragma unroll
    for (int i = 0; i < 8; ++i) acc[i] = 0.f;

    for (int k = beg + part; k < end; k += 4) {
        int s = sorted[k];
        uint4 u = *(const uint4*)&hp[(size_t)s * HID_CH + ch];
        acc[0] += __uint_as_float(u.x << 16);
        acc[1] += __uint_as_float(u.x & 0xffff0000u);
        acc[2] += __uint_as_float(u.y << 16);
        acc[3] += __uint_as_float(u.y & 0xffff0000u);
        acc[4] += __uint_as_float(u.z << 16);
        acc[5] += __uint_as_float(u.z & 0xffff0000u);
        acc[6] += __uint_as_float(u.w << 16);
        acc[7] += __uint_as_float(u.w & 0xffff0000u);
    }

    // combine the 4 edge-parts (lanes 0-15 / 16-31 / 32-47 / 48-63)
#pragma unroll
    for (int i = 0; i < 8; ++i) {
        acc[i] += __shfl_xor(acc[i], 16);
        acc[i] += __shfl_xor(acc[i], 32);
    }

    if (part == 0) {
        float di = dinv[node];
        uint4 us = *(const uint4*)&hp[(size_t)node * HID_CH + ch];
        float sf[8];
        sf[0] = __uint_as_float(us.x << 16);
        sf[1] = __uint_as_float(us.x & 0xffff0000u);
        sf[2] = __uint_as_float(us.y << 16);
        sf[3] = __uint_as_float(us.y & 0xffff0000u);
        sf[4] = __uint_as_float(us.z << 16);
        sf[5] = __uint_as_float(us.z & 0xffff0000u);
        sf[6] = __uint_as_float(us.w << 16);
        sf[7] = __uint_as_float(us.w & 0xffff0000u);

        float4 b0 = *(const float4*)&bias[ch];
        float4 b1 = *(const float4*)&bias[ch + 4];
        float4 a0 = *(const float4*)&alpha[ch];
        float4 a1 = *(const float4*)&alpha[ch + 4];
        float bv[8] = {b0.x, b0.y, b0.z, b0.w, b1.x, b1.y, b1.z, b1.w};
        float av[8] = {a0.x, a0.y, a0.z, a0.w, a1.x, a1.y, a1.z, a1.w};

        float r[8];
#pragma unroll
        for (int i = 0; i < 8; ++i) {
            float v = di * (acc[i] + sf[i]) + bv[i];
            r[i] = v > 0.f ? v : av[i] * v;
        }
        float4 o0 = make_float4(r[0], r[1], r[2], r[3]);
        float4 o1 = make_float4(r[4], r[5], r[6], r[7]);
        *(float4*)&out[(size_t)node * HID_CH + ch] = o0;
        *(float4*)&out[(size_t)node * HID_CH + ch + 4] = o1;
    }
}

// ---------------- launch ----------------

extern "C" void kernel_launch(void* const* d_in, const int* in_sizes, int n_in,
                              void* d_out, int out_size, void* d_ws, size_t ws_size,
                              hipStream_t stream) {
    const float* x     = (const float*)d_in[0];
    const int*   ei    = (const int*)d_in[1];     // [2, E]: [0..E)=src, [E..2E)=dst
    const float* W     = (const float*)d_in[2];
    const float* bias  = (const float*)d_in[3];
    const float* alpha = (const float*)d_in[4];
    float* out = (float*)d_out;

    char* p = (char*)d_ws;
    auto align512 = [](size_t v) { return (v + 511) / 512 * 512; };
    unsigned short* hp = (unsigned short*)p; p += align512((size_t)N_NODES * HID_CH * 2);
    unsigned short* Wt = (unsigned short*)p; p += align512((size_t)IN_CH * HID_CH * 2);
    int* counts    = (int*)p;   p += align512((size_t)N_NODES * 4);
    float* dinv    = (float*)p; p += align512((size_t)N_NODES * 4);
    int* row_start = (int*)p;   p += align512((size_t)(N_NODES + 1) * 4);
    int* rank      = (int*)p;   p += align512((size_t)N_EDGES * 4);
    int* partials  = (int*)p;   p += align512(512 * 4);
    int* sorted    = (int*)p;   p += align512((size_t)N_EDGES * 4);

    hipMemsetAsync(counts, 0, (size_t)N_NODES * sizeof(int), stream);

    count_kernel<<<(N_EDGES + 255) / 256, 256, 0, stream>>>(ei + N_EDGES, counts, rank);
    scanA_kernel<<<SCAN_BLOCKS, 256, 0, stream>>>(counts, row_start, partials);
    scanB_kernel<<<1, 512, 0, stream>>>(partials);
    scanC_kernel<<<SCAN_BLOCKS, 256, 0, stream>>>(row_start, partials, counts, dinv);
    reorder_kernel<<<(N_EDGES + 255) / 256, 256, 0, stream>>>(ei, rank, row_start, sorted);

    wt_kernel<<<(IN_CH * HID_CH + 255) / 256, 256, 0, stream>>>(W, Wt);

    long long gemm_threads = (long long)((N_NODES + 15) / 16) * 64;
    gemm_mfma_kernel<<<(int)((gemm_threads + 255) / 256), 256, 0, stream>>>(x, Wt, dinv, hp);

    long long gthreads = (long long)N_NODES * 64;
    gather_finalize_kernel<<<(int)((gthreads + 255) / 256), 256, 0, stream>>>(
        row_start, sorted, dinv, hp, bias, alpha, out);
}